// Round 1
// baseline (649.740 us; speedup 1.0000x reference)
//
#include <hip/hip_runtime.h>
#include <math.h>

// Top-2 semantics identical to jax.lax.top_k(x, 2):
//   top1 = max, top2 = second element of sorted-desc multiset (duplicates count).
// Branchless update: if v > m1 -> (v, m1 merged into m2) else m2 = max(m2, v).
__device__ __forceinline__ void top2_update(float v, float& m1, float& m2) {
    float nm1 = fmaxf(m1, v);
    m2 = fmaxf(m2, fminf(m1, v));
    m1 = nm1;
}

// Merge two (top1, top2) pairs (each with m1 >= m2) into one.
__device__ __forceinline__ void top2_merge(float o1, float o2, float& m1, float& m2) {
    float hi = fmaxf(m1, o1);
    float lo = fminf(m1, o1);
    m2 = fmaxf(lo, fmaxf(m2, o2));
    m1 = hi;
}

// Monotonic unsigned encoding of float (order-preserving); enc(x) > 0 for all
// finite x, so a zeroed accumulator is a safe identity for atomicMax.
__device__ __forceinline__ unsigned int enc_float(float f) {
    unsigned int b = __float_as_uint(f);
    return (b & 0x80000000u) ? ~b : (b | 0x80000000u);
}

__global__ __launch_bounds__(256) void margin_softmax_kernel(
    const float* __restrict__ out1,
    const float* __restrict__ out2,
    const float* __restrict__ mim,
    const int*   __restrict__ targets,
    float*       __restrict__ d_out,   // [0]=uint-encoded running max, [1 + 3*row + j] = softmax
    int N, int C)
{
    const int lane         = threadIdx.x & 63;
    const int wave_in_blk  = threadIdx.x >> 6;
    const int waves_per_blk = blockDim.x >> 6;
    const int gwave  = blockIdx.x * waves_per_blk + wave_in_blk;
    const int nwaves = gridDim.x * waves_per_blk;

    const int nvec = C >> 2;   // float4 count per row (250 for C=1000)
    const int rem  = C & 3;    // 0 for C=1000

    float lane_run = -INFINITY;  // running max over outputs1 & outputs2

    for (int row = gwave; row < N; row += nwaves) {
        const size_t base = (size_t)row * (size_t)C;
        const float4* p1 = (const float4*)(out1 + base);
        const float4* p2 = (const float4*)(out2 + base);
        const float4* p3 = (const float4*)(mim  + base);

        float a1 = -INFINITY, a2 = -INFINITY;   // outputs1 top-2
        float b1 = -INFINITY, b2 = -INFINITY;   // outputs2 top-2
        float c1 = -INFINITY, c2 = -INFINITY;   // mimic    top-2

        for (int p = lane; p < nvec; p += 64) {
            float4 v1 = p1[p];
            float4 v2 = p2[p];
            float4 v3 = p3[p];
            top2_update(v1.x, a1, a2); top2_update(v1.y, a1, a2);
            top2_update(v1.z, a1, a2); top2_update(v1.w, a1, a2);
            top2_update(v2.x, b1, b2); top2_update(v2.y, b1, b2);
            top2_update(v2.z, b1, b2); top2_update(v2.w, b1, b2);
            top2_update(v3.x, c1, c2); top2_update(v3.y, c1, c2);
            top2_update(v3.z, c1, c2); top2_update(v3.w, c1, c2);
        }
        if (rem && lane < rem) {
            size_t s = base + (size_t)(nvec << 2) + lane;
            top2_update(out1[s], a1, a2);
            top2_update(out2[s], b1, b2);
            top2_update(mim [s], c1, c2);
        }

        // 64-lane butterfly reduce of the three (top1, top2) pairs
        #pragma unroll
        for (int off = 32; off >= 1; off >>= 1) {
            float o1, o2;
            o1 = __shfl_xor(a1, off); o2 = __shfl_xor(a2, off); top2_merge(o1, o2, a1, a2);
            o1 = __shfl_xor(b1, off); o2 = __shfl_xor(b2, off); top2_merge(o1, o2, b1, b2);
            o1 = __shfl_xor(c1, off); o2 = __shfl_xor(c2, off); top2_merge(o1, o2, c1, c2);
        }

        lane_run = fmaxf(lane_run, fmaxf(a1, b1));

        if (lane == 0) {
            int tgt = targets[row];
            float t1 = out1[base + tgt];
            float t2 = out2[base + tgt];
            float t3 = mim [base + tgt];
            // margin = (tgt_logit == top1) ? top1 - top2 : 0   (exact fp equality, same values as ref)
            float d1 = (t1 == a1) ? (a1 - a2) : 0.0f;
            float d2 = (t2 == b1) ? (b1 - b2) : 0.0f;
            float d3 = (t3 == c1) ? (c1 - c2) : 0.0f;
            // softmax over (d1,d2,d3) / T, T = 2.0
            float x1 = d1 * 0.5f, x2 = d2 * 0.5f, x3 = d3 * 0.5f;
            float mx = fmaxf(x1, fmaxf(x2, x3));
            float e1 = expf(x1 - mx), e2 = expf(x2 - mx), e3 = expf(x3 - mx);
            float inv = 1.0f / (e1 + e2 + e3);
            float* o = d_out + 1 + (size_t)row * 3;
            o[0] = e1 * inv;
            o[1] = e2 * inv;
            o[2] = e3 * inv;
        }
    }

    // Reduce lane_run across the wave, then across the block, then one atomic per block.
    #pragma unroll
    for (int off = 32; off >= 1; off >>= 1)
        lane_run = fmaxf(lane_run, __shfl_xor(lane_run, off));

    __shared__ float smax[8];
    if (lane == 0) smax[wave_in_blk] = lane_run;
    __syncthreads();
    if (threadIdx.x == 0) {
        float m = smax[0];
        for (int i = 1; i < waves_per_blk; i++) m = fmaxf(m, smax[i]);
        atomicMax((unsigned int*)d_out, enc_float(m));
    }
}

__global__ void finalize_max_kernel(float* d_out) {
    unsigned int u = ((unsigned int*)d_out)[0];
    unsigned int b = (u & 0x80000000u) ? (u ^ 0x80000000u) : ~u;
    d_out[0] = __uint_as_float(b);
}

extern "C" void kernel_launch(void* const* d_in, const int* in_sizes, int n_in,
                              void* d_out, int out_size, void* d_ws, size_t ws_size,
                              hipStream_t stream) {
    const float* out1    = (const float*)d_in[0];
    const float* out2    = (const float*)d_in[1];
    const float* mim     = (const float*)d_in[2];
    const int*   targets = (const int*)  d_in[3];

    const int N = in_sizes[3];            // 65536
    const int C = in_sizes[0] / N;        // 1000

    // d_out[0] doubles as the uint atomicMax accumulator; enc(x) > 0 for all
    // finite x, so zero is the identity. Decoded in-place by the epilogue.
    (void)hipMemsetAsync(d_out, 0, sizeof(unsigned int), stream);

    // 2048 blocks x 256 threads = 8192 waves = 32 waves/CU; 8 rows per wave.
    margin_softmax_kernel<<<2048, 256, 0, stream>>>(
        out1, out2, mim, targets, (float*)d_out, N, C);

    finalize_max_kernel<<<1, 1, 0, stream>>>((float*)d_out);
}

// Round 2
// 649.307 us; speedup vs baseline: 1.0007x; 1.0007x over previous
//
#include <hip/hip_runtime.h>
#include <math.h>

#define NEG_INF (-__builtin_inff())

// Top-2 semantics identical to jax.lax.top_k(x, 2).
// Branchless update; NEG_INF input is a no-op (safe padding for inactive lanes).
__device__ __forceinline__ void top2_update(float v, float& m1, float& m2) {
    float nm1 = fmaxf(m1, v);
    m2 = fmaxf(m2, fminf(m1, v));
    m1 = nm1;
}

__device__ __forceinline__ void upd4(float4 v, float& m1, float& m2) {
    top2_update(v.x, m1, m2); top2_update(v.y, m1, m2);
    top2_update(v.z, m1, m2); top2_update(v.w, m1, m2);
}

// Merge two (top1, top2) pairs (each with m1 >= m2) into one.
__device__ __forceinline__ void top2_merge(float o1, float o2, float& m1, float& m2) {
    float hi = fmaxf(m1, o1);
    float lo = fminf(m1, o1);
    m2 = fmaxf(lo, fmaxf(m2, o2));
    m1 = hi;
}

// Monotonic unsigned encoding of float (order-preserving); enc(x) > 0 for all
// finite x, so a zeroed accumulator is a safe identity for atomicMax.
__device__ __forceinline__ unsigned int enc_float(float f) {
    unsigned int b = __float_as_uint(f);
    return (b & 0x80000000u) ? ~b : (b | 0x80000000u);
}

// Specialized for C == 1000: 250 float4 per row = 3 full wave-groups + 58-lane tail.
// All 12 row-loads (3 streams x 4 groups, 12 KB/wave) are issued before any
// consumption so the compiler can stagger vmcnt waits -> ~4x in-flight bytes
// vs the rolled loop (which sat at 3 KB/wave and ~3.8 TB/s effective).
__global__ __launch_bounds__(256) void margin_softmax_kernel(
    const float* __restrict__ out1,
    const float* __restrict__ out2,
    const float* __restrict__ mim,
    const int*   __restrict__ targets,
    float*       __restrict__ d_out,   // [0]=uint-encoded running max, [1 + 3*row + j] = softmax
    int N)
{
    const int C = 1000;
    const int lane          = threadIdx.x & 63;
    const int wave_in_blk   = threadIdx.x >> 6;
    const int waves_per_blk = blockDim.x >> 6;
    const int gwave  = blockIdx.x * waves_per_blk + wave_in_blk;
    const int nwaves = gridDim.x * waves_per_blk;

    float lane_run = NEG_INF;  // running max over outputs1 & outputs2

    for (int row = gwave; row < N; row += nwaves) {
        const size_t base = (size_t)row * (size_t)C;
        const float4* p1 = (const float4*)(out1 + base);
        const float4* p2 = (const float4*)(out2 + base);
        const float4* p3 = (const float4*)(mim  + base);

        // Issue all loads up front (9 unconditional + 3 predicated tail loads).
        float4 A0 = p1[lane], A1 = p1[lane + 64], A2 = p1[lane + 128];
        float4 B0 = p2[lane], B1 = p2[lane + 64], B2 = p2[lane + 128];
        float4 M0 = p3[lane], M1 = p3[lane + 64], M2 = p3[lane + 128];
        float4 A3 = make_float4(NEG_INF, NEG_INF, NEG_INF, NEG_INF);
        float4 B3 = A3, M3 = A3;
        if (lane < 58) {        // 250 - 192 = 58 tail float4s
            A3 = p1[lane + 192];
            B3 = p2[lane + 192];
            M3 = p3[lane + 192];
        }

        float a1 = NEG_INF, a2 = NEG_INF;   // outputs1 top-2
        float b1 = NEG_INF, b2 = NEG_INF;   // outputs2 top-2
        float c1 = NEG_INF, c2 = NEG_INF;   // mimic    top-2

        upd4(A0, a1, a2); upd4(A1, a1, a2); upd4(A2, a1, a2); upd4(A3, a1, a2);
        upd4(B0, b1, b2); upd4(B1, b1, b2); upd4(B2, b1, b2); upd4(B3, b1, b2);
        upd4(M0, c1, c2); upd4(M1, c1, c2); upd4(M2, c1, c2); upd4(M3, c1, c2);

        // 64-lane butterfly reduce of the three (top1, top2) pairs
        #pragma unroll
        for (int off = 32; off >= 1; off >>= 1) {
            float o1, o2;
            o1 = __shfl_xor(a1, off); o2 = __shfl_xor(a2, off); top2_merge(o1, o2, a1, a2);
            o1 = __shfl_xor(b1, off); o2 = __shfl_xor(b2, off); top2_merge(o1, o2, b1, b2);
            o1 = __shfl_xor(c1, off); o2 = __shfl_xor(c2, off); top2_merge(o1, o2, c1, c2);
        }

        lane_run = fmaxf(lane_run, fmaxf(a1, b1));

        if (lane == 0) {
            int tgt = targets[row];
            float t1 = out1[base + tgt];   // L1/L2 hit: row just read
            float t2 = out2[base + tgt];
            float t3 = mim [base + tgt];
            // margin = (tgt_logit == top1) ? top1 - top2 : 0  (exact fp equality, same values as ref)
            float d1 = (t1 == a1) ? (a1 - a2) : 0.0f;
            float d2 = (t2 == b1) ? (b1 - b2) : 0.0f;
            float d3 = (t3 == c1) ? (c1 - c2) : 0.0f;
            // softmax over (d1,d2,d3) / T, T = 2.0
            float x1 = d1 * 0.5f, x2 = d2 * 0.5f, x3 = d3 * 0.5f;
            float mx = fmaxf(x1, fmaxf(x2, x3));
            float e1 = expf(x1 - mx), e2 = expf(x2 - mx), e3 = expf(x3 - mx);
            float inv = 1.0f / (e1 + e2 + e3);
            float* o = d_out + 1 + (size_t)row * 3;
            o[0] = e1 * inv;
            o[1] = e2 * inv;
            o[2] = e3 * inv;
        }
    }

    // Reduce lane_run across the wave, then across the block, then one atomic per block.
    #pragma unroll
    for (int off = 32; off >= 1; off >>= 1)
        lane_run = fmaxf(lane_run, __shfl_xor(lane_run, off));

    __shared__ float smax[8];
    if (lane == 0) smax[wave_in_blk] = lane_run;
    __syncthreads();
    if (threadIdx.x == 0) {
        float m = smax[0];
        for (int i = 1; i < waves_per_blk; i++) m = fmaxf(m, smax[i]);
        atomicMax((unsigned int*)d_out, enc_float(m));
    }
}

__global__ void finalize_max_kernel(float* d_out) {
    unsigned int u = ((unsigned int*)d_out)[0];
    unsigned int b = (u & 0x80000000u) ? (u ^ 0x80000000u) : ~u;
    d_out[0] = __uint_as_float(b);
}

extern "C" void kernel_launch(void* const* d_in, const int* in_sizes, int n_in,
                              void* d_out, int out_size, void* d_ws, size_t ws_size,
                              hipStream_t stream) {
    const float* out1    = (const float*)d_in[0];
    const float* out2    = (const float*)d_in[1];
    const float* mim     = (const float*)d_in[2];
    const int*   targets = (const int*)  d_in[3];

    const int N = in_sizes[3];            // 65536 (C fixed at 1000 in the kernel)

    // d_out[0] doubles as the uint atomicMax accumulator; enc(x) > 0 for all
    // finite x, so zero is the identity. Decoded in-place by the epilogue.
    (void)hipMemsetAsync(d_out, 0, sizeof(unsigned int), stream);

    // 2048 blocks x 256 threads = 8192 waves; 8 rows per wave.
    margin_softmax_kernel<<<2048, 256, 0, stream>>>(
        out1, out2, mim, targets, (float*)d_out, N);

    finalize_max_kernel<<<1, 1, 0, stream>>>((float*)d_out);
}